// Round 1
// baseline (749.040 us; speedup 1.0000x reference)
//
#include <hip/hip_runtime.h>
#include <cmath>

#define MP1 524288
#define NXP 32768
#define PP  128
#define HTN 128
#define HEN 64

// ws layout (float offsets):
//   [0,128)              b_acc (must be zeroed; ws is poisoned each launch)
//   [128,256)            cvec = Wt3^T (b_acc+bb)
//   [256]                u_const = dot(b, bt3)
//   [512, 512+16384)     WT2t[k*128+j] = Wt2[j*128+k]
//   [16896, 16896+4096)  WE2t[i*64+m]  = We2[m*64+i]

__global__ __launch_bounds__(256) void prep1_k(const float* __restrict__ Wt2,
                                               const float* __restrict__ We2,
                                               float* __restrict__ ws) {
    int idx = blockIdx.x * 256 + threadIdx.x;
    if (idx < 128) ws[idx] = 0.0f;
    if (idx < 16384) {
        int j = idx >> 7, k = idx & 127;
        ws[512 + k * 128 + j] = Wt2[idx];
    }
    if (idx < 4096) {
        int m = idx >> 6, i = idx & 63;
        ws[16896 + i * 64 + m] = We2[idx];
    }
}

// b_acc[row] += sum over one 16384-float chunk of Wb[row,:] * a[:]
__global__ __launch_bounds__(256) void gemv_k(const float* __restrict__ Wb,
                                              const float* __restrict__ a,
                                              float* __restrict__ b_acc) {
    const int row = blockIdx.y;
    const int chunk = blockIdx.x;
    const int t = threadIdx.x;
    size_t base = (size_t)row * MP1 + (size_t)chunk * 16384;
    const float4* W4 = (const float4*)(Wb + base);
    const float4* A4 = (const float4*)(a + (size_t)chunk * 16384);
    float sum = 0.0f;
#pragma unroll
    for (int it = 0; it < 16; ++it) {
        float4 w = W4[t + it * 256];
        float4 av = A4[t + it * 256];
        sum += w.x * av.x + w.y * av.y + w.z * av.z + w.w * av.w;
    }
#pragma unroll
    for (int off = 32; off > 0; off >>= 1) sum += __shfl_down(sum, off, 64);
    __shared__ float red[4];
    int wid = t >> 6;
    if ((t & 63) == 0) red[wid] = sum;
    __syncthreads();
    if (t == 0) atomicAdd(&b_acc[row], red[0] + red[1] + red[2] + red[3]);
}

// cvec[k] = sum_j (b_acc[j]+bb[j]) * Wt3[j,k];  u_const = sum_j b_j*bt3[j]
__global__ __launch_bounds__(128) void prep2_k(const float* __restrict__ ws_in,
                                               const float* __restrict__ bb,
                                               const float* __restrict__ Wt3,
                                               const float* __restrict__ bt3,
                                               float* __restrict__ ws) {
    int k = threadIdx.x;
    float cv = 0.0f;
    for (int j = 0; j < 128; ++j)
        cv = fmaf(ws_in[j] + bb[j], Wt3[j * 128 + k], cv);
    ws[128 + k] = cv;
    float p = (ws_in[k] + bb[k]) * bt3[k];
#pragma unroll
    for (int off = 32; off > 0; off >>= 1) p += __shfl_down(p, off, 64);
    __shared__ float red[2];
    if ((k & 63) == 0) red[k >> 6] = p;
    __syncthreads();
    if (k == 0) ws[256] = red[0] + red[1];
}

__global__ __launch_bounds__(64, 1) void point_k(const float* __restrict__ x,
                                                 const float* __restrict__ tptr,
                                                 const float* __restrict__ Wt1,
                                                 const float* __restrict__ bt1,
                                                 const float* __restrict__ bt2,
                                                 const float* __restrict__ We1,
                                                 const float* __restrict__ be1,
                                                 const float* __restrict__ be2,
                                                 const float* __restrict__ We3,
                                                 const float* __restrict__ ws,
                                                 float* __restrict__ out) {
    const int tid = threadIdx.x;
    const int i = blockIdx.x * 64 + tid;
    const float xi = x[i];
    const float tt = tptr[0];
    const float* __restrict__ cvec = ws + 128;
    const float* __restrict__ WT2t = ws + 512;
    const float* __restrict__ WE2t = ws + 16896;

    __shared__ float h1v[128 * 64];  // trunk layer-1 tanh values, [k][tid]
    __shared__ float h1e[64 * 64];   // energy layer-1 tanh values, [i][tid]

    // ---- Phase A: trunk layer-1 values (jets recomputed from value later) ----
#pragma unroll 4
    for (int k = 0; k < 128; ++k) {
        float w0 = Wt1[2 * k], w1 = Wt1[2 * k + 1];
        float z = fmaf(w0, xi, fmaf(w1, tt, bt1[k]));
        h1v[k * 64 + tid] = tanhf(z);
    }

    // ---- Phase B: trunk layer-2 jets + u jets ----
    float u0 = ws[256], u1 = 0.f, u2 = 0.f, u3 = 0.f;  // u, u_x, u_xx, u_xxx
    for (int g = 0; g < 4; ++g) {
        float a0[32], a1[32], a2[32], a3[32];
#pragma unroll
        for (int jj = 0; jj < 32; ++jj) { a0[jj] = 0.f; a1[jj] = 0.f; a2[jj] = 0.f; a3[jj] = 0.f; }
#pragma unroll 2
        for (int k = 0; k < 128; ++k) {
            float v = h1v[k * 64 + tid];
            float w = Wt1[2 * k];           // dz/dx is the x-weight
            float s = 1.f - v * v;
            float f2 = -2.f * v * s;
            float f3 = 2.f * s * (2.f * v * v - s);
            float d1 = s * w;
            float d2 = f2 * w * w;
            float d3 = f3 * w * w * w;
            const float* wrow = WT2t + k * 128 + g * 32;
#pragma unroll
            for (int jj = 0; jj < 32; ++jj) {
                float wjk = wrow[jj];
                a0[jj] = fmaf(wjk, v, a0[jj]);
                a1[jj] = fmaf(wjk, d1, a1[jj]);
                a2[jj] = fmaf(wjk, d2, a2[jj]);
                a3[jj] = fmaf(wjk, d3, a3[jj]);
            }
        }
#pragma unroll
        for (int jj = 0; jj < 32; ++jj) {
            int j = g * 32 + jj;
            float z0 = a0[jj] + bt2[j];
            float z1 = a1[jj], z2 = a2[jj], z3 = a3[jj];
            float v = tanhf(z0);
            float s = 1.f - v * v;
            float f2 = -2.f * v * s;
            float f3 = 2.f * s * (2.f * v * v - s);
            float h0 = v;
            float h1 = s * z1;
            float h2 = f2 * z1 * z1 + s * z2;
            float h3 = f3 * z1 * z1 * z1 + 3.f * f2 * z1 * z2 + s * z3;
            float cj = cvec[j];
            u0 = fmaf(cj, h0, u0);
            u1 = fmaf(cj, h1, u1);
            u2 = fmaf(cj, h2, u2);
            u3 = fmaf(cj, h3, u3);
        }
    }

    // ---- Phase C: EnergyNet partials at (y,z) = (u, u_x) ----
    const float y = u0, z = u1;
#pragma unroll 4
    for (int ii = 0; ii < 64; ++ii) {
        float w0 = We1[2 * ii], w1 = We1[2 * ii + 1];
        float g = fmaf(w0, y, fmaf(w1, z, be1[ii]));
        h1e[ii * 64 + tid] = tanhf(g);
    }

    float Fyy = 0.f, Fyz = 0.f, Fzz = 0.f, Fyyz = 0.f, Fyzz = 0.f, Fzzz = 0.f;
    for (int g4 = 0; g4 < 4; ++g4) {
        float A0[16], A1[16], A2[16], A3[16], A4[16], A5[16], A6[16], A7[16], A8[16];
#pragma unroll
        for (int mm = 0; mm < 16; ++mm) {
            A0[mm] = 0.f; A1[mm] = 0.f; A2[mm] = 0.f; A3[mm] = 0.f; A4[mm] = 0.f;
            A5[mm] = 0.f; A6[mm] = 0.f; A7[mm] = 0.f; A8[mm] = 0.f;
        }
#pragma unroll 2
        for (int ii = 0; ii < 64; ++ii) {
            float v = h1e[ii * 64 + tid];
            float w0 = We1[2 * ii], w1 = We1[2 * ii + 1];
            float s = 1.f - v * v;
            float f2 = -2.f * v * s;
            float f3 = 2.f * s * (2.f * v * v - s);
            // layer-1 jets (pre-activation affine -> 2nd/3rd pre-act jets vanish)
            float j1 = s * w0, j2 = s * w1;
            float j3 = f2 * w0 * w0, j4 = f2 * w0 * w1, j5 = f2 * w1 * w1;
            float j6 = f3 * w0 * w0 * w1, j7 = f3 * w0 * w1 * w1, j8 = f3 * w1 * w1 * w1;
            const float* wrow = WE2t + ii * 64 + g4 * 16;
#pragma unroll
            for (int mm = 0; mm < 16; ++mm) {
                float wmi = wrow[mm];
                A0[mm] = fmaf(wmi, v,  A0[mm]);
                A1[mm] = fmaf(wmi, j1, A1[mm]);
                A2[mm] = fmaf(wmi, j2, A2[mm]);
                A3[mm] = fmaf(wmi, j3, A3[mm]);
                A4[mm] = fmaf(wmi, j4, A4[mm]);
                A5[mm] = fmaf(wmi, j5, A5[mm]);
                A6[mm] = fmaf(wmi, j6, A6[mm]);
                A7[mm] = fmaf(wmi, j7, A7[mm]);
                A8[mm] = fmaf(wmi, j8, A8[mm]);
            }
        }
#pragma unroll
        for (int mm = 0; mm < 16; ++mm) {
            int m = g4 * 16 + mm;
            float G0 = A0[mm] + be2[m];
            float v = tanhf(G0);
            float s = 1.f - v * v;
            float f2 = -2.f * v * s;
            float f3 = 2.f * s * (2.f * v * v - s);
            float Gy = A1[mm], Gz = A2[mm];
            float Gyy = A3[mm], Gyz = A4[mm], Gzz = A5[mm];
            float Gyyz = A6[mm], Gyzz = A7[mm], Gzzz = A8[mm];
            float Hyy = f2 * Gy * Gy + s * Gyy;
            float Hyz = f2 * Gy * Gz + s * Gyz;
            float Hzz = f2 * Gz * Gz + s * Gzz;
            float Hyyz = f3 * Gy * Gy * Gz + f2 * (Gyy * Gz + 2.f * Gyz * Gy) + s * Gyyz;
            float Hyzz = f3 * Gy * Gz * Gz + f2 * (2.f * Gyz * Gz + Gzz * Gy) + s * Gyzz;
            float Hzzz = f3 * Gz * Gz * Gz + 3.f * f2 * Gzz * Gz + s * Gzzz;
            float w3 = We3[m];
            Fyy  = fmaf(w3, Hyy,  Fyy);
            Fyz  = fmaf(w3, Hyz,  Fyz);
            Fzz  = fmaf(w3, Hzz,  Fzz);
            Fyyz = fmaf(w3, Hyyz, Fyyz);
            Fyzz = fmaf(w3, Hyzz, Fyzz);
            Fzzz = fmaf(w3, Hzzz, Fzzz);
        }
    }

    // ---- combine ----
    float F_yx  = Fyy * u1 + Fyz * u2;
    float F_zxx = Fyz * u2 + Fzz * u3 + Fyyz * u1 * u1
                + 2.f * Fyzz * u1 * u2 + Fzzz * u2 * u2;
    out[i] = F_zxx - F_yx;
}

extern "C" void kernel_launch(void* const* d_in, const int* in_sizes, int n_in,
                              void* d_out, int out_size, void* d_ws, size_t ws_size,
                              hipStream_t stream) {
    const float* a   = (const float*)d_in[0];
    const float* x   = (const float*)d_in[1];
    const float* t   = (const float*)d_in[2];
    const float* Wb  = (const float*)d_in[3];
    const float* bb  = (const float*)d_in[4];
    const float* Wt1 = (const float*)d_in[5];
    const float* bt1 = (const float*)d_in[6];
    const float* Wt2 = (const float*)d_in[7];
    const float* bt2 = (const float*)d_in[8];
    const float* Wt3 = (const float*)d_in[9];
    const float* bt3 = (const float*)d_in[10];
    const float* We1 = (const float*)d_in[11];
    const float* be1 = (const float*)d_in[12];
    const float* We2 = (const float*)d_in[13];
    const float* be2 = (const float*)d_in[14];
    const float* We3 = (const float*)d_in[15];
    // be3 (d_in[16]) contributes only to F's value, never to its derivatives.

    float* ws = (float*)d_ws;
    float* out = (float*)d_out;

    prep1_k<<<64, 256, 0, stream>>>(Wt2, We2, ws);
    gemv_k<<<dim3(32, 128), 256, 0, stream>>>(Wb, a, ws);
    prep2_k<<<1, 128, 0, stream>>>(ws, bb, Wt3, bt3, ws);
    point_k<<<NXP / 64, 64, 0, stream>>>(x, t, Wt1, bt1, bt2, We1, be1, be2, We3,
                                         ws, out);
}

// Round 2
// 508.010 us; speedup vs baseline: 1.4745x; 1.4745x over previous
//
#include <hip/hip_runtime.h>
#include <cmath>

#define MP1 524288
#define NXP 32768

// ws layout (float offsets):
//   [0,128)              b_acc (zeroed by prep1; ws is poisoned each launch)
//   [128,256)            cvec = Wt3^T (b_acc+bb)
//   [256]                u_const = dot(b, bt3)
//   [512, 512+16384)     WT2t[k*128+j] = Wt2[j*128+k]
//   [16896, 16896+4096)  WE2t[i*64+m]  = We2[m*64+i]

__global__ __launch_bounds__(256) void prep1_k(const float* __restrict__ Wt2,
                                               const float* __restrict__ We2,
                                               float* __restrict__ ws) {
    int idx = blockIdx.x * 256 + threadIdx.x;
    if (idx < 128) ws[idx] = 0.0f;
    if (idx < 16384) {
        int j = idx >> 7, k = idx & 127;
        ws[512 + k * 128 + j] = Wt2[idx];
    }
    if (idx < 4096) {
        int m = idx >> 6, i = idx & 63;
        ws[16896 + i * 64 + m] = We2[idx];
    }
}

__global__ __launch_bounds__(256) void gemv_k(const float* __restrict__ Wb,
                                              const float* __restrict__ a,
                                              float* __restrict__ b_acc) {
    const int row = blockIdx.y;
    const int chunk = blockIdx.x;
    const int t = threadIdx.x;
    size_t base = (size_t)row * MP1 + (size_t)chunk * 16384;
    const float4* W4 = (const float4*)(Wb + base);
    const float4* A4 = (const float4*)(a + (size_t)chunk * 16384);
    float sum = 0.0f;
#pragma unroll
    for (int it = 0; it < 16; ++it) {
        float4 w = W4[t + it * 256];
        float4 av = A4[t + it * 256];
        sum += w.x * av.x + w.y * av.y + w.z * av.z + w.w * av.w;
    }
#pragma unroll
    for (int off = 32; off > 0; off >>= 1) sum += __shfl_down(sum, off, 64);
    __shared__ float red[4];
    int wid = t >> 6;
    if ((t & 63) == 0) red[wid] = sum;
    __syncthreads();
    if (t == 0) atomicAdd(&b_acc[row], red[0] + red[1] + red[2] + red[3]);
}

__global__ __launch_bounds__(128) void prep2_k(const float* __restrict__ ws_in,
                                               const float* __restrict__ bb,
                                               const float* __restrict__ Wt3,
                                               const float* __restrict__ bt3,
                                               float* __restrict__ ws) {
    int k = threadIdx.x;
    float cv = 0.0f;
    for (int j = 0; j < 128; ++j)
        cv = fmaf(ws_in[j] + bb[j], Wt3[j * 128 + k], cv);
    ws[128 + k] = cv;
    float p = (ws_in[k] + bb[k]) * bt3[k];
#pragma unroll
    for (int off = 32; off > 0; off >>= 1) p += __shfl_down(p, off, 64);
    __shared__ float red[2];
    if ((k & 63) == 0) red[k >> 6] = p;
    __syncthreads();
    if (k == 0) ws[256] = red[0] + red[1];
}

// 512 threads = 8 wave-aligned slices x 64 points. Slice s owns trunk outputs
// j in [16s,16s+16) and energy outputs m in [8s,8s+8). lane = point, so all
// weight-row indexing is wave-uniform -> scalar loads.
#define H1V 0          // 8192 floats: trunk layer-1 tanh [k*64+p]; h1e aliases [0,4096) later
#define RED 8192       // 2048 floats: per-slice u partials [(s*64+p)*4+r]
#define URED 10240     // 256 floats:  reduced u jets [p*4+r]
#define FRED 10496     // 3072 floats: per-slice F partials [(s*64+p)*6+q]
#define LDSF 13568

__global__ __launch_bounds__(512, 4) void point_k(const float* __restrict__ x,
                                                  const float* __restrict__ tptr,
                                                  const float* __restrict__ Wt1,
                                                  const float* __restrict__ bt1,
                                                  const float* __restrict__ bt2,
                                                  const float* __restrict__ We1,
                                                  const float* __restrict__ be1,
                                                  const float* __restrict__ be2,
                                                  const float* __restrict__ We3,
                                                  const float* __restrict__ ws,
                                                  float* __restrict__ out) {
    __shared__ float lds[LDSF];
    const int tid = threadIdx.x;
    const int p = tid & 63;
    const int slice = tid >> 6;
    const int i = blockIdx.x * 64 + p;
    const float xi = x[i];
    const float tt = tptr[0];
    const float* __restrict__ cvec = ws + 128;
    const float* __restrict__ WT2t = ws + 512;
    const float* __restrict__ WE2t = ws + 16896;

    // ---- Phase A: trunk layer-1 tanh values (16 k's per thread) ----
#pragma unroll
    for (int q = 0; q < 16; ++q) {
        int k = slice * 16 + q;
        float z = fmaf(Wt1[2 * k], xi, fmaf(Wt1[2 * k + 1], tt, bt1[k]));
        lds[H1V + k * 64 + p] = tanhf(z);
    }
    __syncthreads();

    // ---- Phase B: trunk layer-2 jets, this slice's 16 j's ----
    {
        float a0[16], a1[16], a2[16], a3[16];
#pragma unroll
        for (int jj = 0; jj < 16; ++jj) { a0[jj] = 0.f; a1[jj] = 0.f; a2[jj] = 0.f; a3[jj] = 0.f; }
#pragma unroll 2
        for (int k = 0; k < 128; ++k) {
            float v = lds[H1V + k * 64 + p];
            float w = Wt1[2 * k];
            float s = 1.f - v * v;
            float f2 = -2.f * v * s;
            float f3 = 2.f * s * (2.f * v * v - s);
            float d1 = s * w;
            float d2 = f2 * w * w;
            float d3 = f3 * w * w * w;
            const float* wrow = WT2t + k * 128 + slice * 16;
#pragma unroll
            for (int jj = 0; jj < 16; ++jj) {
                float wjk = wrow[jj];
                a0[jj] = fmaf(wjk, v, a0[jj]);
                a1[jj] = fmaf(wjk, d1, a1[jj]);
                a2[jj] = fmaf(wjk, d2, a2[jj]);
                a3[jj] = fmaf(wjk, d3, a3[jj]);
            }
        }
        float u0 = 0.f, u1 = 0.f, u2 = 0.f, u3 = 0.f;
#pragma unroll
        for (int jj = 0; jj < 16; ++jj) {
            int j = slice * 16 + jj;
            float z0 = a0[jj] + bt2[j];
            float z1 = a1[jj], z2 = a2[jj], z3 = a3[jj];
            float v = tanhf(z0);
            float s = 1.f - v * v;
            float f2 = -2.f * v * s;
            float f3 = 2.f * s * (2.f * v * v - s);
            float cj = cvec[j];
            u0 = fmaf(cj, v, u0);
            u1 = fmaf(cj, s * z1, u1);
            u2 = fmaf(cj, f2 * z1 * z1 + s * z2, u2);
            u3 = fmaf(cj, f3 * z1 * z1 * z1 + 3.f * f2 * z1 * z2 + s * z3, u3);
        }
        float* r = lds + RED + (slice * 64 + p) * 4;
        r[0] = u0; r[1] = u1; r[2] = u2; r[3] = u3;
    }
    __syncthreads();

    // ---- reduce u jets across slices (threads 0..63) ----
    if (tid < 64) {
        float u0 = ws[256], u1 = 0.f, u2 = 0.f, u3 = 0.f;
#pragma unroll
        for (int s = 0; s < 8; ++s) {
            const float* r = lds + RED + (s * 64 + tid) * 4;
            u0 += r[0]; u1 += r[1]; u2 += r[2]; u3 += r[3];
        }
        float* u = lds + URED + tid * 4;
        u[0] = u0; u[1] = u1; u[2] = u2; u[3] = u3;
    }
    __syncthreads();

    const float y = lds[URED + p * 4 + 0];
    const float z = lds[URED + p * 4 + 1];

    // ---- Phase C part 1: energy layer-1 tanh values (8 ii's per thread) ----
    // h1e aliases the (dead) h1v region.
#pragma unroll
    for (int q = 0; q < 8; ++q) {
        int ii = slice * 8 + q;
        float g = fmaf(We1[2 * ii], y, fmaf(We1[2 * ii + 1], z, be1[ii]));
        lds[H1V + ii * 64 + p] = tanhf(g);
    }
    __syncthreads();

    // ---- Phase C part 2: energy layer-2 jets, this slice's 8 m's ----
    {
        float A0[8], A1[8], A2[8], A3[8], A4[8], A5[8], A6[8], A7[8], A8[8];
#pragma unroll
        for (int mm = 0; mm < 8; ++mm) {
            A0[mm] = 0.f; A1[mm] = 0.f; A2[mm] = 0.f; A3[mm] = 0.f; A4[mm] = 0.f;
            A5[mm] = 0.f; A6[mm] = 0.f; A7[mm] = 0.f; A8[mm] = 0.f;
        }
#pragma unroll 2
        for (int ii = 0; ii < 64; ++ii) {
            float v = lds[H1V + ii * 64 + p];
            float w0 = We1[2 * ii], w1 = We1[2 * ii + 1];
            float s = 1.f - v * v;
            float f2 = -2.f * v * s;
            float f3 = 2.f * s * (2.f * v * v - s);
            float j1 = s * w0, j2 = s * w1;
            float j3 = f2 * w0 * w0, j4 = f2 * w0 * w1, j5 = f2 * w1 * w1;
            float j6 = f3 * w0 * w0 * w1, j7 = f3 * w0 * w1 * w1, j8 = f3 * w1 * w1 * w1;
            const float* wrow = WE2t + ii * 64 + slice * 8;
#pragma unroll
            for (int mm = 0; mm < 8; ++mm) {
                float wmi = wrow[mm];
                A0[mm] = fmaf(wmi, v,  A0[mm]);
                A1[mm] = fmaf(wmi, j1, A1[mm]);
                A2[mm] = fmaf(wmi, j2, A2[mm]);
                A3[mm] = fmaf(wmi, j3, A3[mm]);
                A4[mm] = fmaf(wmi, j4, A4[mm]);
                A5[mm] = fmaf(wmi, j5, A5[mm]);
                A6[mm] = fmaf(wmi, j6, A6[mm]);
                A7[mm] = fmaf(wmi, j7, A7[mm]);
                A8[mm] = fmaf(wmi, j8, A8[mm]);
            }
        }
        float Fyy = 0.f, Fyz = 0.f, Fzz = 0.f, Fyyz = 0.f, Fyzz = 0.f, Fzzz = 0.f;
#pragma unroll
        for (int mm = 0; mm < 8; ++mm) {
            int m = slice * 8 + mm;
            float G0 = A0[mm] + be2[m];
            float v = tanhf(G0);
            float s = 1.f - v * v;
            float f2 = -2.f * v * s;
            float f3 = 2.f * s * (2.f * v * v - s);
            float Gy = A1[mm], Gz = A2[mm];
            float Gyy = A3[mm], Gyz = A4[mm], Gzz = A5[mm];
            float Hyy = f2 * Gy * Gy + s * Gyy;
            float Hyz = f2 * Gy * Gz + s * Gyz;
            float Hzz = f2 * Gz * Gz + s * Gzz;
            float Hyyz = f3 * Gy * Gy * Gz + f2 * (Gyy * Gz + 2.f * Gyz * Gy) + s * A6[mm];
            float Hyzz = f3 * Gy * Gz * Gz + f2 * (2.f * Gyz * Gz + Gzz * Gy) + s * A7[mm];
            float Hzzz = f3 * Gz * Gz * Gz + 3.f * f2 * Gzz * Gz + s * A8[mm];
            float w3 = We3[m];
            Fyy  = fmaf(w3, Hyy,  Fyy);
            Fyz  = fmaf(w3, Hyz,  Fyz);
            Fzz  = fmaf(w3, Hzz,  Fzz);
            Fyyz = fmaf(w3, Hyyz, Fyyz);
            Fyzz = fmaf(w3, Hyzz, Fyzz);
            Fzzz = fmaf(w3, Hzzz, Fzzz);
        }
        float* r = lds + FRED + (slice * 64 + p) * 6;
        r[0] = Fyy; r[1] = Fyz; r[2] = Fzz; r[3] = Fyyz; r[4] = Fyzz; r[5] = Fzzz;
    }
    __syncthreads();

    // ---- reduce F partials + combine (threads 0..63) ----
    if (tid < 64) {
        float F[6] = {0.f, 0.f, 0.f, 0.f, 0.f, 0.f};
#pragma unroll
        for (int s = 0; s < 8; ++s) {
            const float* r = lds + FRED + (s * 64 + tid) * 6;
#pragma unroll
            for (int q = 0; q < 6; ++q) F[q] += r[q];
        }
        const float* u = lds + URED + tid * 4;
        float u1 = u[1], u2 = u[2], u3 = u[3];
        float F_yx  = F[0] * u1 + F[1] * u2;
        float F_zxx = F[1] * u2 + F[2] * u3 + F[3] * u1 * u1
                    + 2.f * F[4] * u1 * u2 + F[5] * u2 * u2;
        out[blockIdx.x * 64 + tid] = F_zxx - F_yx;
    }
}

extern "C" void kernel_launch(void* const* d_in, const int* in_sizes, int n_in,
                              void* d_out, int out_size, void* d_ws, size_t ws_size,
                              hipStream_t stream) {
    const float* a   = (const float*)d_in[0];
    const float* x   = (const float*)d_in[1];
    const float* t   = (const float*)d_in[2];
    const float* Wb  = (const float*)d_in[3];
    const float* bb  = (const float*)d_in[4];
    const float* Wt1 = (const float*)d_in[5];
    const float* bt1 = (const float*)d_in[6];
    const float* Wt2 = (const float*)d_in[7];
    const float* bt2 = (const float*)d_in[8];
    const float* Wt3 = (const float*)d_in[9];
    const float* bt3 = (const float*)d_in[10];
    const float* We1 = (const float*)d_in[11];
    const float* be1 = (const float*)d_in[12];
    const float* We2 = (const float*)d_in[13];
    const float* be2 = (const float*)d_in[14];
    const float* We3 = (const float*)d_in[15];

    float* ws = (float*)d_ws;
    float* out = (float*)d_out;

    prep1_k<<<64, 256, 0, stream>>>(Wt2, We2, ws);
    gemv_k<<<dim3(32, 128), 256, 0, stream>>>(Wb, a, ws);
    prep2_k<<<1, 128, 0, stream>>>(ws, bb, Wt3, bt3, ws);
    point_k<<<NXP / 64, 512, 0, stream>>>(x, t, Wt1, bt1, bt2, We1, be1, be2, We3,
                                          ws, out);
}

// Round 3
// 492.755 us; speedup vs baseline: 1.5201x; 1.0310x over previous
//
#include <hip/hip_runtime.h>
#include <cmath>

#define MP1 524288
#define NXP 32768

// ws layout (float offsets):
//   [0,128)              b_acc (zeroed by prep1; ws is poisoned each launch)
//   [128,256)            cvec = Wt3^T (b_acc+bb)
//   [256]                u_const = dot(b, bt3)
//   [512, 512+16384)     WT2t[k*128+j] = Wt2[j*128+k]
//   [16896, 16896+4096)  WE2t[i*64+m]  = We2[m*64+i]

__global__ __launch_bounds__(256) void prep1_k(const float* __restrict__ Wt2,
                                               const float* __restrict__ We2,
                                               float* __restrict__ ws) {
    int idx = blockIdx.x * 256 + threadIdx.x;
    if (idx < 128) ws[idx] = 0.0f;
    if (idx < 16384) {
        int j = idx >> 7, k = idx & 127;
        ws[512 + k * 128 + j] = Wt2[idx];
    }
    if (idx < 4096) {
        int m = idx >> 6, i = idx & 63;
        ws[16896 + i * 64 + m] = We2[idx];
    }
}

__global__ __launch_bounds__(256) void gemv_k(const float* __restrict__ Wb,
                                              const float* __restrict__ a,
                                              float* __restrict__ b_acc) {
    const int row = blockIdx.y;
    const int chunk = blockIdx.x;
    const int t = threadIdx.x;
    size_t base = (size_t)row * MP1 + (size_t)chunk * 16384;
    const float4* W4 = (const float4*)(Wb + base);
    const float4* A4 = (const float4*)(a + (size_t)chunk * 16384);
    float sum = 0.0f;
#pragma unroll
    for (int it = 0; it < 16; ++it) {
        float4 w = W4[t + it * 256];
        float4 av = A4[t + it * 256];
        sum += w.x * av.x + w.y * av.y + w.z * av.z + w.w * av.w;
    }
#pragma unroll
    for (int off = 32; off > 0; off >>= 1) sum += __shfl_down(sum, off, 64);
    __shared__ float red[4];
    int wid = t >> 6;
    if ((t & 63) == 0) red[wid] = sum;
    __syncthreads();
    if (t == 0) atomicAdd(&b_acc[row], red[0] + red[1] + red[2] + red[3]);
}

__global__ __launch_bounds__(128) void prep2_k(const float* __restrict__ ws_in,
                                               const float* __restrict__ bb,
                                               const float* __restrict__ Wt3,
                                               const float* __restrict__ bt3,
                                               float* __restrict__ ws) {
    int k = threadIdx.x;
    float cv = 0.0f;
    for (int j = 0; j < 128; ++j)
        cv = fmaf(ws_in[j] + bb[j], Wt3[j * 128 + k], cv);
    ws[128 + k] = cv;
    float p = (ws_in[k] + bb[k]) * bt3[k];
#pragma unroll
    for (int off = 32; off > 0; off >>= 1) p += __shfl_down(p, off, 64);
    __shared__ float red[2];
    if ((k & 63) == 0) red[k >> 6] = p;
    __syncthreads();
    if (k == 0) ws[256] = red[0] + red[1];
}

// 512 threads = 8 wave-aligned slices x 64 points. Slice s owns trunk outputs
// j in [16s,16s+16) and energy outputs m in [8s,8s+8). lane = point. slice is
// wave-uniform; readfirstlane makes it PROVABLY uniform so all weight-row
// reads lower to s_load_dwordx16/x8 (SMEM pipe) instead of 2048 per-wave
// global_load_dword broadcasts competing with the FMA stream.
#define H1V 0          // 8192 floats: trunk layer-1 tanh [k*64+p]; h1e aliases [0,4096) later
#define RED 8192       // 2048 floats: per-slice u partials [(s*64+p)*4+r]
#define URED 10240     // 256 floats:  reduced u jets [p*4+r]
#define FRED 10496     // 3072 floats: per-slice F partials [(s*64+p)*6+q]
#define LDSF 13568

__global__ __launch_bounds__(512, 4) void point_k(const float* __restrict__ x,
                                                  const float* __restrict__ tptr,
                                                  const float* __restrict__ Wt1,
                                                  const float* __restrict__ bt1,
                                                  const float* __restrict__ bt2,
                                                  const float* __restrict__ We1,
                                                  const float* __restrict__ be1,
                                                  const float* __restrict__ be2,
                                                  const float* __restrict__ We3,
                                                  const float* __restrict__ ws,
                                                  float* __restrict__ out) {
    __shared__ float lds[LDSF];
    const int tid = threadIdx.x;
    const int p = tid & 63;
    const int slice = __builtin_amdgcn_readfirstlane(tid >> 6);
    const int i = blockIdx.x * 64 + p;
    const float xi = x[i];
    const float tt = tptr[0];
    const float* __restrict__ cvec = ws + 128;
    const float* __restrict__ WT2t = ws + 512;
    const float* __restrict__ WE2t = ws + 16896;
    const float u_const = ws[256];

    // ---- Phase A: trunk layer-1 tanh values (16 k's per thread) ----
#pragma unroll
    for (int q = 0; q < 16; ++q) {
        int k = slice * 16 + q;
        float z = fmaf(Wt1[2 * k], xi, fmaf(Wt1[2 * k + 1], tt, bt1[k]));
        lds[H1V + k * 64 + p] = tanhf(z);
    }
    __syncthreads();

    // ---- Phase B: trunk layer-2 jets, this slice's 16 j's ----
    {
        float a0[16], a1[16], a2[16], a3[16];
#pragma unroll
        for (int jj = 0; jj < 16; ++jj) { a0[jj] = 0.f; a1[jj] = 0.f; a2[jj] = 0.f; a3[jj] = 0.f; }
#pragma unroll 2
        for (int k = 0; k < 128; ++k) {
            float v = lds[H1V + k * 64 + p];
            float w = Wt1[2 * k];            // uniform (loop index) -> s_load
            float s = 1.f - v * v;
            float f2 = -2.f * v * s;
            float f3 = 2.f * s * (2.f * v * v - s);
            float d1 = s * w;
            float d2 = f2 * w * w;
            float d3 = f3 * w * w * w;
            const float* wrow = WT2t + k * 128 + slice * 16;  // uniform -> s_load_dwordx16
#pragma unroll
            for (int jj = 0; jj < 16; ++jj) {
                float wjk = wrow[jj];
                a0[jj] = fmaf(wjk, v, a0[jj]);
                a1[jj] = fmaf(wjk, d1, a1[jj]);
                a2[jj] = fmaf(wjk, d2, a2[jj]);
                a3[jj] = fmaf(wjk, d3, a3[jj]);
            }
        }
        float u0 = 0.f, u1 = 0.f, u2 = 0.f, u3 = 0.f;
#pragma unroll
        for (int jj = 0; jj < 16; ++jj) {
            int j = slice * 16 + jj;         // uniform
            float z0 = a0[jj] + bt2[j];
            float z1 = a1[jj], z2 = a2[jj], z3 = a3[jj];
            float v = tanhf(z0);
            float s = 1.f - v * v;
            float f2 = -2.f * v * s;
            float f3 = 2.f * s * (2.f * v * v - s);
            float cj = cvec[j];
            u0 = fmaf(cj, v, u0);
            u1 = fmaf(cj, s * z1, u1);
            u2 = fmaf(cj, f2 * z1 * z1 + s * z2, u2);
            u3 = fmaf(cj, f3 * z1 * z1 * z1 + 3.f * f2 * z1 * z2 + s * z3, u3);
        }
        float* r = lds + RED + (slice * 64 + p) * 4;
        r[0] = u0; r[1] = u1; r[2] = u2; r[3] = u3;
    }
    __syncthreads();

    // ---- reduce u jets across slices (threads 0..63) ----
    if (tid < 64) {
        float u0 = u_const, u1 = 0.f, u2 = 0.f, u3 = 0.f;
#pragma unroll
        for (int s = 0; s < 8; ++s) {
            const float* r = lds + RED + (s * 64 + tid) * 4;
            u0 += r[0]; u1 += r[1]; u2 += r[2]; u3 += r[3];
        }
        float* u = lds + URED + tid * 4;
        u[0] = u0; u[1] = u1; u[2] = u2; u[3] = u3;
    }
    __syncthreads();

    const float y = lds[URED + p * 4 + 0];
    const float z = lds[URED + p * 4 + 1];

    // ---- Phase C part 1: energy layer-1 tanh values (8 ii's per thread) ----
#pragma unroll
    for (int q = 0; q < 8; ++q) {
        int ii = slice * 8 + q;
        float g = fmaf(We1[2 * ii], y, fmaf(We1[2 * ii + 1], z, be1[ii]));
        lds[H1V + ii * 64 + p] = tanhf(g);
    }
    __syncthreads();

    // ---- Phase C part 2: energy layer-2 jets, this slice's 8 m's ----
    {
        float A0[8], A1[8], A2[8], A3[8], A4[8], A5[8], A6[8], A7[8], A8[8];
#pragma unroll
        for (int mm = 0; mm < 8; ++mm) {
            A0[mm] = 0.f; A1[mm] = 0.f; A2[mm] = 0.f; A3[mm] = 0.f; A4[mm] = 0.f;
            A5[mm] = 0.f; A6[mm] = 0.f; A7[mm] = 0.f; A8[mm] = 0.f;
        }
#pragma unroll 2
        for (int ii = 0; ii < 64; ++ii) {
            float v = lds[H1V + ii * 64 + p];
            float w0 = We1[2 * ii], w1 = We1[2 * ii + 1];  // uniform -> s_load
            float s = 1.f - v * v;
            float f2 = -2.f * v * s;
            float f3 = 2.f * s * (2.f * v * v - s);
            float j1 = s * w0, j2 = s * w1;
            float j3 = f2 * w0 * w0, j4 = f2 * w0 * w1, j5 = f2 * w1 * w1;
            float j6 = f3 * w0 * w0 * w1, j7 = f3 * w0 * w1 * w1, j8 = f3 * w1 * w1 * w1;
            const float* wrow = WE2t + ii * 64 + slice * 8;  // uniform -> s_load_dwordx8
#pragma unroll
            for (int mm = 0; mm < 8; ++mm) {
                float wmi = wrow[mm];
                A0[mm] = fmaf(wmi, v,  A0[mm]);
                A1[mm] = fmaf(wmi, j1, A1[mm]);
                A2[mm] = fmaf(wmi, j2, A2[mm]);
                A3[mm] = fmaf(wmi, j3, A3[mm]);
                A4[mm] = fmaf(wmi, j4, A4[mm]);
                A5[mm] = fmaf(wmi, j5, A5[mm]);
                A6[mm] = fmaf(wmi, j6, A6[mm]);
                A7[mm] = fmaf(wmi, j7, A7[mm]);
                A8[mm] = fmaf(wmi, j8, A8[mm]);
            }
        }
        float Fyy = 0.f, Fyz = 0.f, Fzz = 0.f, Fyyz = 0.f, Fyzz = 0.f, Fzzz = 0.f;
#pragma unroll
        for (int mm = 0; mm < 8; ++mm) {
            int m = slice * 8 + mm;          // uniform
            float G0 = A0[mm] + be2[m];
            float v = tanhf(G0);
            float s = 1.f - v * v;
            float f2 = -2.f * v * s;
            float f3 = 2.f * s * (2.f * v * v - s);
            float Gy = A1[mm], Gz = A2[mm];
            float Gyy = A3[mm], Gyz = A4[mm], Gzz = A5[mm];
            float Hyy = f2 * Gy * Gy + s * Gyy;
            float Hyz = f2 * Gy * Gz + s * Gyz;
            float Hzz = f2 * Gz * Gz + s * Gzz;
            float Hyyz = f3 * Gy * Gy * Gz + f2 * (Gyy * Gz + 2.f * Gyz * Gy) + s * A6[mm];
            float Hyzz = f3 * Gy * Gz * Gz + f2 * (2.f * Gyz * Gz + Gzz * Gy) + s * A7[mm];
            float Hzzz = f3 * Gz * Gz * Gz + 3.f * f2 * Gzz * Gz + s * A8[mm];
            float w3 = We3[m];
            Fyy  = fmaf(w3, Hyy,  Fyy);
            Fyz  = fmaf(w3, Hyz,  Fyz);
            Fzz  = fmaf(w3, Hzz,  Fzz);
            Fyyz = fmaf(w3, Hyyz, Fyyz);
            Fyzz = fmaf(w3, Hyzz, Fyzz);
            Fzzz = fmaf(w3, Hzzz, Fzzz);
        }
        float* r = lds + FRED + (slice * 64 + p) * 6;
        r[0] = Fyy; r[1] = Fyz; r[2] = Fzz; r[3] = Fyyz; r[4] = Fyzz; r[5] = Fzzz;
    }
    __syncthreads();

    // ---- reduce F partials + combine (threads 0..63) ----
    if (tid < 64) {
        float F[6] = {0.f, 0.f, 0.f, 0.f, 0.f, 0.f};
#pragma unroll
        for (int s = 0; s < 8; ++s) {
            const float* r = lds + FRED + (s * 64 + tid) * 6;
#pragma unroll
            for (int q = 0; q < 6; ++q) F[q] += r[q];
        }
        const float* u = lds + URED + tid * 4;
        float u1 = u[1], u2 = u[2], u3 = u[3];
        float F_yx  = F[0] * u1 + F[1] * u2;
        float F_zxx = F[1] * u2 + F[2] * u3 + F[3] * u1 * u1
                    + 2.f * F[4] * u1 * u2 + F[5] * u2 * u2;
        out[blockIdx.x * 64 + tid] = F_zxx - F_yx;
    }
}

extern "C" void kernel_launch(void* const* d_in, const int* in_sizes, int n_in,
                              void* d_out, int out_size, void* d_ws, size_t ws_size,
                              hipStream_t stream) {
    const float* a   = (const float*)d_in[0];
    const float* x   = (const float*)d_in[1];
    const float* t   = (const float*)d_in[2];
    const float* Wb  = (const float*)d_in[3];
    const float* bb  = (const float*)d_in[4];
    const float* Wt1 = (const float*)d_in[5];
    const float* bt1 = (const float*)d_in[6];
    const float* Wt2 = (const float*)d_in[7];
    const float* bt2 = (const float*)d_in[8];
    const float* Wt3 = (const float*)d_in[9];
    const float* bt3 = (const float*)d_in[10];
    const float* We1 = (const float*)d_in[11];
    const float* be1 = (const float*)d_in[12];
    const float* We2 = (const float*)d_in[13];
    const float* be2 = (const float*)d_in[14];
    const float* We3 = (const float*)d_in[15];

    float* ws = (float*)d_ws;
    float* out = (float*)d_out;

    prep1_k<<<64, 256, 0, stream>>>(Wt2, We2, ws);
    gemv_k<<<dim3(32, 128), 256, 0, stream>>>(Wb, a, ws);
    prep2_k<<<1, 128, 0, stream>>>(ws, bb, Wt3, bt3, ws);
    point_k<<<NXP / 64, 512, 0, stream>>>(x, t, Wt1, bt1, bt2, We1, be1, be2, We3,
                                          ws, out);
}